// Round 6
// baseline (95.435 us; speedup 1.0000x reference)
//
#include <hip/hip_runtime.h>

#define BATCH 32
#define IC 16
#define OC 32
#define SI 32
#define KS 3
#define SO 30

#define ROWS 4                 // output rows per band
#define XROWS (ROWS + KS - 1)  // 6 input rows staged
#define XCOLS 36               // 144 B rows = 9 float4; cols 32..35 zero pad
#define NBANDS 8
#define WPT (IC * KS * KS)     // 144 weights per oc
#define NROW (IC * XROWS)      // 96 staged LDS rows
#define NV4  (NROW * 9)        // 864 float4 slots (8 data + 1 pad per row)

// grid: batch(32) x band(8) x ochalf(2) = 512 blocks x 512 thr
//   -> 2 blocks/CU, 16 waves/CU, 4 waves/SIMD (R5 had 2: staging barrier
//      exposed). Two co-resident blocks interleave staging with compute.
// Each wave owns an oc PAIR (uniform -> weights via s_load, no LDS for w).
__global__ __launch_bounds__(512) void conv3x3_kernel(
    const float* __restrict__ x, const float* __restrict__ w,
    const float* __restrict__ bias, float* __restrict__ out)
{
    __shared__ __align__(16) float xs[IC][XROWS][XCOLS];  // 13.8 KB

    const int t    = threadIdx.x;
    const int blk  = blockIdx.x;
    const int band = blk & (NBANDS - 1);
    const int g    = (blk >> 3) & 1;   // oc half
    const int b    = blk >> 4;         // batch
    const int row0 = band * ROWS;

    // ---- stage input band, float4-vectorized ----
    // LDS row stride 144 B (16B-aligned); slot q==8 is the 16 B zero pad.
    const float* xb = x + b * (IC * SI * SI);
    for (int idx = t; idx < NV4; idx += 512) {
        const int r  = idx / 9;        // LDS row 0..95 = ic*6 + ii
        const int q  = idx - r * 9;    // float4 slot 0..8
        const int ic = r / XROWS;
        const int ii = r - ic * XROWS;
        const int gi = row0 + ii;
        float4 v = make_float4(0.f, 0.f, 0.f, 0.f);
        if (q < 8 && gi < SI)
            v = *reinterpret_cast<const float4*>(&xb[ic * SI * SI + gi * SI + q * 4]);
        *reinterpret_cast<float4*>(&xs[ic][ii][q * 4]) = v;
    }
    __syncthreads();

    // ---- wave-uniform oc pair: weights through SGPRs ----
    const int wvid = __builtin_amdgcn_readfirstlane(t >> 6);  // 0..7, uniform
    const int oc0  = g * 16 + wvid * 2;
    const float* __restrict__ wq = w + oc0 * WPT;             // uniform base

    const int l  = t & 63;
    const int il = l >> 4;        // local row 0..3
    const int c  = (l & 15) * 2;  // col base 0,2,...,30 (c==30 lane is dead)

    float acc[2][2] = {{0.f}};    // [oo][jj]

    // unroll capped (R1 lesson: full unroll -> VGPR=256 + spill)
    #pragma unroll 2
    for (int ic = 0; ic < IC; ++ic) {
        #pragma unroll
        for (int k1 = 0; k1 < KS; ++k1) {
            // 4-wide x window (cols c..c+3), two aligned b64 reads
            const float2 xa = *reinterpret_cast<const float2*>(&xs[ic][il + k1][c]);
            const float2 xc = *reinterpret_cast<const float2*>(&xs[ic][il + k1][c + 2]);
            const float xw[4] = {xa.x, xa.y, xc.x, xc.y};
            #pragma unroll
            for (int k2 = 0; k2 < KS; ++k2) {
                const float wv0 = wq[ic * 9 + k1 * 3 + k2];        // s_load
                const float wv1 = wq[WPT + ic * 9 + k1 * 3 + k2];  // s_load
                acc[0][0] = fmaf(wv0, xw[k2],     acc[0][0]);
                acc[0][1] = fmaf(wv0, xw[k2 + 1], acc[0][1]);
                acc[1][0] = fmaf(wv1, xw[k2],     acc[1][0]);
                acc[1][1] = fmaf(wv1, xw[k2 + 1], acc[1][1]);
            }
        }
    }

    // ---- epilogue: bias + float2 store (8B aligned, c even) ----
    const int i = row0 + il;
    if (i < SO && c < SO) {
        #pragma unroll
        for (int oo = 0; oo < 2; ++oo) {
            const int oc = oc0 + oo;
            const float bs = bias[oc];
            float* orow = out + ((size_t)(b * OC + oc) * SO + i) * SO;
            *reinterpret_cast<float2*>(&orow[c]) =
                make_float2(acc[oo][0] + bs, acc[oo][1] + bs);
        }
    }
}

extern "C" void kernel_launch(void* const* d_in, const int* in_sizes, int n_in,
                              void* d_out, int out_size, void* d_ws, size_t ws_size,
                              hipStream_t stream) {
    const float* x    = (const float*)d_in[0];
    const float* w    = (const float*)d_in[1];
    const float* bias = (const float*)d_in[2];
    // d_in[3..5] (rows/cols/param_idx) encode a dense 3x3 valid conv — unused.
    float* out = (float*)d_out;

    conv3x3_kernel<<<dim3(BATCH * NBANDS * 2), dim3(512), 0, stream>>>(x, w, bias, out);
}

// Round 7
// 94.487 us; speedup vs baseline: 1.0100x; 1.0100x over previous
//
#include <hip/hip_runtime.h>

#define BATCH 32
#define IC 16
#define OC 32
#define SI 32
#define KS 3
#define SO 30

#define ROWS 4                 // output rows per band
#define XROWS (ROWS + KS - 1)  // 6 input rows staged
#define XCOLS 36               // 144 B rows = 9 float4; cols 32..35 zero pad
#define NBANDS 8
#define WPT (IC * KS * KS)     // 144 weights per oc
#define NROW (IC * XROWS)      // 96 staged LDS rows
#define NV4  (NROW * 9)        // 864 float4 slots (8 data + 1 pad per row)

// R7 = exact revert to R5 (measured best, 94.5 us).
// grid: batch(32) x band(8) = 256 blocks x 512 thr -> 1 block/CU,
// 8 waves/CU = 2 waves/SIMD. Wave w owns oc quad w*4.. (uniform -> s_load
// weights, no LDS for w). x staged ONCE per (b,band) — R6's 2x staging
// (for 4 waves/SIMD) measured 0.9 us WORSE.
__global__ __launch_bounds__(512) void conv3x3_kernel(
    const float* __restrict__ x, const float* __restrict__ w,
    const float* __restrict__ bias, float* __restrict__ out)
{
    __shared__ __align__(16) float xs[IC][XROWS][XCOLS];  // 13.8 KB

    const int t    = threadIdx.x;
    const int blk  = blockIdx.x;
    const int band = blk & (NBANDS - 1);
    const int b    = blk >> 3;
    const int row0 = band * ROWS;

    // ---- stage input band, float4-vectorized ----
    // LDS row stride 144 B (16B-aligned); slot q==8 is the 16 B zero pad.
    const float* xb = x + b * (IC * SI * SI);
    for (int idx = t; idx < NV4; idx += 512) {
        const int r  = idx / 9;        // LDS row 0..95 = ic*6 + ii
        const int q  = idx - r * 9;    // float4 slot 0..8
        const int ic = r / XROWS;
        const int ii = r - ic * XROWS;
        const int gi = row0 + ii;
        float4 v = make_float4(0.f, 0.f, 0.f, 0.f);
        if (q < 8 && gi < SI)
            v = *reinterpret_cast<const float4*>(&xb[ic * SI * SI + gi * SI + q * 4]);
        *reinterpret_cast<float4*>(&xs[ic][ii][q * 4]) = v;
    }
    __syncthreads();

    // ---- wave-uniform oc quad: weights through SGPRs ----
    const int wvid = __builtin_amdgcn_readfirstlane(t >> 6);  // 0..7, uniform
    const int oc0  = wvid * 4;
    const float* __restrict__ wq = w + oc0 * WPT;             // uniform base

    const int l  = t & 63;
    const int il = l >> 4;        // local row 0..3
    const int c  = (l & 15) * 2;  // col base 0,2,...,30 (c==30 lane reads pad, no store)

    float acc[4][2] = {{0.f}};    // [oo][jj]

    // unroll capped (R1 lesson: full unroll -> VGPR=256 + spill)
    #pragma unroll 2
    for (int ic = 0; ic < IC; ++ic) {
        #pragma unroll
        for (int k1 = 0; k1 < KS; ++k1) {
            // 4-wide x window (cols c..c+3), two aligned b64 reads
            const float2 xa = *reinterpret_cast<const float2*>(&xs[ic][il + k1][c]);
            const float2 xc = *reinterpret_cast<const float2*>(&xs[ic][il + k1][c + 2]);
            const float xw[4] = {xa.x, xa.y, xc.x, xc.y};
            #pragma unroll
            for (int k2 = 0; k2 < KS; ++k2) {
                #pragma unroll
                for (int oo = 0; oo < 4; ++oo) {
                    const float wv = wq[oo * WPT + ic * 9 + k1 * 3 + k2]; // s_load
                    acc[oo][0] = fmaf(wv, xw[k2],     acc[oo][0]);
                    acc[oo][1] = fmaf(wv, xw[k2 + 1], acc[oo][1]);
                }
            }
        }
    }

    // ---- epilogue: bias + float2 store (8B aligned, c even) ----
    const int i = row0 + il;
    if (i < SO && c < SO) {
        #pragma unroll
        for (int oo = 0; oo < 4; ++oo) {
            const int oc = oc0 + oo;
            const float bs = bias[oc];
            float* orow = out + ((size_t)(b * OC + oc) * SO + i) * SO;
            *reinterpret_cast<float2*>(&orow[c]) =
                make_float2(acc[oo][0] + bs, acc[oo][1] + bs);
        }
    }
}

extern "C" void kernel_launch(void* const* d_in, const int* in_sizes, int n_in,
                              void* d_out, int out_size, void* d_ws, size_t ws_size,
                              hipStream_t stream) {
    const float* x    = (const float*)d_in[0];
    const float* w    = (const float*)d_in[1];
    const float* bias = (const float*)d_in[2];
    // d_in[3..5] (rows/cols/param_idx) encode a dense 3x3 valid conv — unused.
    float* out = (float*)d_out;

    conv3x3_kernel<<<dim3(BATCH * NBANDS), dim3(512), 0, stream>>>(x, w, bias, out);
}